// Round 3
// baseline (240.880 us; speedup 1.0000x reference)
//
#include <hip/hip_runtime.h>

#define IN_FEAT 64
#define OUT_FEAT 64
#define CAP 64   // padded-CSR capacity; deg ~ Poisson(16), P(>64) ~ e^-42
#define NSHARD 8
#define BLKS_PER_SHARD 256
#define UNROLL 7 // ceil(E4 / threads-per-shard) = ceil(400000/65536)

typedef __attribute__((ext_vector_type(8))) _Float16 half8;
typedef __attribute__((ext_vector_type(4))) float floatx4;
typedef __attribute__((ext_vector_type(4))) int intx4;   // clang vector: ok for nontemporal builtin

// ---- K0: h (f32) -> h16 (f16), 8 elems/thread. ----
__global__ __launch_bounds__(256) void conv_kernel(const float* __restrict__ h,
        _Float16* __restrict__ h16, int total8) {
    int t = blockIdx.x * 256 + threadIdx.x;
    if (t >= total8) return;
    const float4* p = (const float4*)(h + (long long)t * 8);
    float4 a = p[0], c = p[1];
    half8 v;
    v[0] = (_Float16)a.x; v[1] = (_Float16)a.y;
    v[2] = (_Float16)a.z; v[3] = (_Float16)a.w;
    v[4] = (_Float16)c.x; v[5] = (_Float16)c.y;
    v[6] = (_Float16)c.z; v[7] = (_Float16)c.w;
    *(half8*)(h16 + (long long)t * 8) = v;
}

// ---- K1: XCD-sharded padded-CSR fill, MLP-batched. ----
// shard = blockIdx % 8 = XCD id under round-robin dispatch; per-shard
// deg+csr window (50KB + 3.2MB) stays L2-resident on one XCD.
// R1 counters showed occupancy 80% but HBM 22%, VALU 5%: latency-bound at
// ~1.3 outstanding scattered reqs/wave (serialized dst->src->atomic->store
// chain). Fix: one fully-unrolled batch of 7 int4 (28 edges) per thread,
// three phases (all dst loads | all src loads + atomics | all stores) so
// each wave keeps ~10+ scattered requests in flight. dst reads are
// non-temporal: zero reuse within a shard, keeps csr window in L2.
__global__ __launch_bounds__(256) void fill_kernel(const int* __restrict__ src,
        const int* __restrict__ dst, int* __restrict__ deg,
        int* __restrict__ csr, int E, int shard_sz) {
    int shard = blockIdx.x & (NSHARD - 1);
    int blk   = blockIdx.x >> 3;            // 0..BLKS_PER_SHARD-1
    int lo = shard * shard_sz;
    int hi = lo + shard_sz;
    const int stride = BLKS_PER_SHARD * 256;   // 65536 threads per shard
    int E4 = E >> 2;
    const intx4* dst4 = (const intx4*)dst;

    for (int base = blk * 256 + (int)threadIdx.x; base < E4;
         base += stride * UNROLL) {
        // Phase A: issue all dst loads (independent -> all in flight).
        intx4 d[UNROLL];
#pragma unroll
        for (int j = 0; j < UNROLL; ++j) {
            int i = base + j * stride;
            if (i < E4) d[j] = __builtin_nontemporal_load(&dst4[i]);
            else        d[j] = (intx4){-1, -1, -1, -1};
        }
        // Phase B: matched edges -> src load + deg atomic, results kept in
        // unroll-indexed register arrays (static indices -> no scratch).
        int sv[UNROLL * 4];
        int pv[UNROLL * 4];
#pragma unroll
        for (int j = 0; j < UNROLL; ++j) {
            int e = (base + j * stride) << 2;
            int dd0 = d[j].x, dd1 = d[j].y, dd2 = d[j].z, dd3 = d[j].w;
            if (dd0 >= lo && dd0 < hi) {
                sv[j * 4 + 0] = src[e + 0];
                pv[j * 4 + 0] = atomicAdd(&deg[dd0], 1);
            }
            if (dd1 >= lo && dd1 < hi) {
                sv[j * 4 + 1] = src[e + 1];
                pv[j * 4 + 1] = atomicAdd(&deg[dd1], 1);
            }
            if (dd2 >= lo && dd2 < hi) {
                sv[j * 4 + 2] = src[e + 2];
                pv[j * 4 + 2] = atomicAdd(&deg[dd2], 1);
            }
            if (dd3 >= lo && dd3 < hi) {
                sv[j * 4 + 3] = src[e + 3];
                pv[j * 4 + 3] = atomicAdd(&deg[dd3], 1);
            }
        }
        // Phase C: stores (mask recomputed from d[] to avoid a bool array).
#pragma unroll
        for (int j = 0; j < UNROLL; ++j) {
            int dd0 = d[j].x, dd1 = d[j].y, dd2 = d[j].z, dd3 = d[j].w;
            if (dd0 >= lo && dd0 < hi && pv[j * 4 + 0] < CAP)
                csr[(dd0 << 6) | pv[j * 4 + 0]] = sv[j * 4 + 0];
            if (dd1 >= lo && dd1 < hi && pv[j * 4 + 1] < CAP)
                csr[(dd1 << 6) | pv[j * 4 + 1]] = sv[j * 4 + 1];
            if (dd2 >= lo && dd2 < hi && pv[j * 4 + 2] < CAP)
                csr[(dd2 << 6) | pv[j * 4 + 2]] = sv[j * 4 + 2];
            if (dd3 >= lo && dd3 < hi && pv[j * 4 + 3] < CAP)
                csr[(dd3 << 6) | pv[j * 4 + 3]] = sv[j * 4 + 3];
        }
    }
    // tail (E % 4 != 0; dead for E = 1.6M but kept for generality)
    if (blk == 0) {
        for (int e = ((E >> 2) << 2) + (int)threadIdx.x; e < E; e += 256) {
            int dd = dst[e];
            if (dd >= lo && dd < hi) {
                int s = src[e];
                int pos = atomicAdd(&deg[dd], 1);
                if (pos < CAP) csr[(dd << 6) | pos] = s;
            }
        }
    }
}

// ---- K2: gather-mean over f16 h rows (128B/row). One wave per node, ----
// 8 nodes serially per wave; 8-deep load batches, dual accumulators.
// Writes x[n] = [h16[n] | mean f16] aliased over csr row n.
__global__ __launch_bounds__(256) void gather_kernel(const _Float16* __restrict__ h16,
        const int* __restrict__ deg, int* csr_x, int N) {
    int wave = threadIdx.x >> 6;
    int lane = threadIdx.x & 63;
    int n0 = (blockIdx.x * 4 + wave) * 8;
    if (n0 >= N) return;
    for (int i = 0; i < 8; ++i) {
        int n = n0 + i;
        if (n >= N) return;
        int cnt = deg[n];
        int m = cnt < CAP ? cnt : CAP;
        int sid = (lane < m) ? csr_x[(n << 6) | lane] : 0;  // coalesced 256B
        _Float16 selfh = h16[(long long)n * IN_FEAT + lane];
        float acc0 = 0.0f, acc1 = 0.0f;
        int j = 0;
        for (; j + 8 <= m; j += 8) {
            int s0 = __shfl(sid, j);
            int s1 = __shfl(sid, j + 1);
            int s2 = __shfl(sid, j + 2);
            int s3 = __shfl(sid, j + 3);
            int s4 = __shfl(sid, j + 4);
            int s5 = __shfl(sid, j + 5);
            int s6 = __shfl(sid, j + 6);
            int s7 = __shfl(sid, j + 7);
            float a0 = (float)h16[(long long)s0 * IN_FEAT + lane];
            float a1 = (float)h16[(long long)s1 * IN_FEAT + lane];
            float a2 = (float)h16[(long long)s2 * IN_FEAT + lane];
            float a3 = (float)h16[(long long)s3 * IN_FEAT + lane];
            float a4 = (float)h16[(long long)s4 * IN_FEAT + lane];
            float a5 = (float)h16[(long long)s5 * IN_FEAT + lane];
            float a6 = (float)h16[(long long)s6 * IN_FEAT + lane];
            float a7 = (float)h16[(long long)s7 * IN_FEAT + lane];
            acc0 += (a0 + a1) + (a2 + a3);
            acc1 += (a4 + a5) + (a6 + a7);
        }
        if (j + 4 <= m) {
            int s0 = __shfl(sid, j);
            int s1 = __shfl(sid, j + 1);
            int s2 = __shfl(sid, j + 2);
            int s3 = __shfl(sid, j + 3);
            float a0 = (float)h16[(long long)s0 * IN_FEAT + lane];
            float a1 = (float)h16[(long long)s1 * IN_FEAT + lane];
            float a2 = (float)h16[(long long)s2 * IN_FEAT + lane];
            float a3 = (float)h16[(long long)s3 * IN_FEAT + lane];
            acc1 += (a0 + a1) + (a2 + a3);
            j += 4;
        }
        for (; j < m; ++j)
            acc0 += (float)h16[(long long)__shfl(sid, j) * IN_FEAT + lane];
        float mean = (acc0 + acc1) / fmaxf((float)cnt, 1.0f);
        _Float16* xr = (_Float16*)(csr_x + ((long long)n << 6));
        xr[lane] = selfh;
        xr[IN_FEAT + lane] = (_Float16)mean;
    }
}

// ---- K3: MFMA linear. 16 nodes/wave, 4 waves/block, no LDS. ----
// Reads x (f16) from ws only; writes d_out — safe to overwrite h16 region.
__global__ __launch_bounds__(256) void linear_kernel(const int* __restrict__ x_i,
        const float* __restrict__ W, const float* __restrict__ b,
        float* __restrict__ out, int N) {
    const _Float16* x = (const _Float16*)x_i;
    int wave = threadIdx.x >> 6;
    int lane = threadIdx.x & 63;
    int quad = lane >> 4;
    int l16  = lane & 15;

    // bf[t][q][j] = B[k=32q+8quad+j][n=16t+l16] = W[16t+l16][32q+8quad+j]
    half8 bf[4][4];
#pragma unroll
    for (int t = 0; t < 4; ++t)
#pragma unroll
        for (int q = 0; q < 4; ++q) {
            const float* wp = W + (16 * t + l16) * (2 * IN_FEAT) + 32 * q + 8 * quad;
            half8 v;
#pragma unroll
            for (int j = 0; j < 8; ++j) v[j] = (_Float16)wp[j];
            bf[t][q] = v;
        }
    float bias[4];
#pragma unroll
    for (int t = 0; t < 4; ++t) bias[t] = b[16 * t + l16];

    int node_base = (blockIdx.x * 4 + wave) * 16;
    if (node_base >= N) return;
    int mrow = node_base + l16;
    if (mrow >= N) mrow = N - 1;

    floatx4 z = {0.0f, 0.0f, 0.0f, 0.0f};
    floatx4 acc[4] = {z, z, z, z};
#pragma unroll
    for (int q = 0; q < 4; ++q) {
        half8 af = *(const half8*)&x[(long long)mrow * (2 * IN_FEAT) + 32 * q + 8 * quad];
#pragma unroll
        for (int t = 0; t < 4; ++t)
            acc[t] = __builtin_amdgcn_mfma_f32_16x16x32_f16(af, bf[t][q], acc[t], 0, 0, 0);
    }
#pragma unroll
    for (int t = 0; t < 4; ++t)
#pragma unroll
        for (int r = 0; r < 4; ++r) {
            int n = node_base + quad * 4 + r;
            if (n < N)
                out[(long long)n * OUT_FEAT + 16 * t + l16] = acc[t][r] + bias[t];
        }
}

extern "C" void kernel_launch(void* const* d_in, const int* in_sizes, int n_in,
                              void* d_out, int out_size, void* d_ws, size_t ws_size,
                              hipStream_t stream) {
    const float* h   = (const float*)d_in[0];
    const int*   src = (const int*)d_in[1];
    const int*   dst = (const int*)d_in[2];
    const float* W   = (const float*)d_in[3];
    const float* b   = (const float*)d_in[4];
    float* out = (float*)d_out;

    int N = in_sizes[0] / IN_FEAT;   // 100000
    int E = in_sizes[1];             // 1600000

    // ws (ints): deg[N] | csr[N*64] (x[N][128] f16 aliased over csr) = 26 MB
    int* deg = (int*)d_ws;
    int* csr = deg + N;
    // h16 lives in the front 12.8 MB of d_out (dead until linear_kernel
    // rewrites d_out; linear reads only from ws -> no race).
    _Float16* h16 = (_Float16*)out;

    (void)hipMemsetAsync(deg, 0, (size_t)N * sizeof(int), stream);

    int total8 = N * IN_FEAT / 8;
    conv_kernel<<<(total8 + 255) / 256, 256, 0, stream>>>(h, h16, total8);

    int shard_sz = (N + NSHARD - 1) / NSHARD;   // 12500
    fill_kernel<<<NSHARD * BLKS_PER_SHARD, 256, 0, stream>>>(src, dst, deg, csr, E, shard_sz);

    int gather_blocks = (N + 31) / 32;       // 4 waves x 8 nodes per block
    gather_kernel<<<gather_blocks, 256, 0, stream>>>(h16, deg, csr, N);

    int tiles = (N + 15) / 16;
    linear_kernel<<<(tiles + 3) / 4, 256, 0, stream>>>(csr, W, b, out, N);
}

// Round 4
// 210.667 us; speedup vs baseline: 1.1434x; 1.1434x over previous
//
#include <hip/hip_runtime.h>

#define IN_FEAT 64
#define OUT_FEAT 64
#define CAP 64   // padded-CSR capacity; deg ~ Poisson(16), P(>64) ~ e^-42
#define NSHARD 8
#define BLKS_PER_SHARD 256

typedef __attribute__((ext_vector_type(8))) _Float16 half8;
typedef __attribute__((ext_vector_type(4))) float floatx4;

// ---- K0: h (f32) -> h16 (f16), 8 elems/thread. ----
__global__ __launch_bounds__(256) void conv_kernel(const float* __restrict__ h,
        _Float16* __restrict__ h16, int total8) {
    int t = blockIdx.x * 256 + threadIdx.x;
    if (t >= total8) return;
    const float4* p = (const float4*)(h + (long long)t * 8);
    float4 a = p[0], c = p[1];
    half8 v;
    v[0] = (_Float16)a.x; v[1] = (_Float16)a.y;
    v[2] = (_Float16)a.z; v[3] = (_Float16)a.w;
    v[4] = (_Float16)c.x; v[5] = (_Float16)c.y;
    v[6] = (_Float16)c.z; v[7] = (_Float16)c.w;
    *(half8*)(h16 + (long long)t * 8) = v;
}

// ---- K1: XCD-sharded padded-CSR fill (R1 structure, proven 75us). ----
// Pinned at ~75us across occupancy 22-80% and MLP 1-28: scattered-
// transaction throughput wall (~3 scattered ops/edge), not latency.
__global__ __launch_bounds__(256) void fill_kernel(const int* __restrict__ src,
        const int* __restrict__ dst, int* __restrict__ deg,
        int* __restrict__ csr, int E, int shard_sz) {
    int shard = blockIdx.x & (NSHARD - 1);
    int blk   = blockIdx.x >> 3;            // 0..BLKS_PER_SHARD-1
    int lo = shard * shard_sz;
    int hi = lo + shard_sz;
    int stride = BLKS_PER_SHARD * 256;
    int E4 = E >> 2;
    const int4* dst4 = (const int4*)dst;
    for (int e4 = blk * 256 + threadIdx.x; e4 < E4; e4 += stride) {
        int4 d = dst4[e4];
        int e = e4 << 2;
        if (d.x >= lo && d.x < hi) {
            int s = src[e];
            int pos = atomicAdd(&deg[d.x], 1);
            if (pos < CAP) csr[(d.x << 6) | pos] = s;
        }
        if (d.y >= lo && d.y < hi) {
            int s = src[e + 1];
            int pos = atomicAdd(&deg[d.y], 1);
            if (pos < CAP) csr[(d.y << 6) | pos] = s;
        }
        if (d.z >= lo && d.z < hi) {
            int s = src[e + 2];
            int pos = atomicAdd(&deg[d.z], 1);
            if (pos < CAP) csr[(d.z << 6) | pos] = s;
        }
        if (d.w >= lo && d.w < hi) {
            int s = src[e + 3];
            int pos = atomicAdd(&deg[d.w], 1);
            if (pos < CAP) csr[(d.w << 6) | pos] = s;
        }
    }
    // tail (E % 4 != 0; dead for E = 1.6M but kept for generality)
    if (blk == 0) {
        for (int e = (E4 << 2) + threadIdx.x; e < E; e += 256) {
            int dd = dst[e];
            if (dd >= lo && dd < hi) {
                int s = src[e];
                int pos = atomicAdd(&deg[dd], 1);
                if (pos < CAP) csr[(dd << 6) | pos] = s;
            }
        }
    }
}

// ---- K2: gather-mean, 2-node interleaved chains. ----
// v2: 4 nodes/wave as 2 pairs; each pair's neighbor batches interleave
// (16 outstanding row-reads/wave vs 8), serial chain depth halved.
// Full-8 batches with wave-uniform masked adds replace the 4/1 tails;
// sid sanitized to 0 for lane>=m so over-batch loads hit h16[0] (safe).
__global__ __launch_bounds__(256) void gather_kernel(const _Float16* __restrict__ h16,
        const int* __restrict__ deg, int* csr_x, int N) {
    int wave = threadIdx.x >> 6;
    int lane = threadIdx.x & 63;
    int n0 = (blockIdx.x * 4 + wave) * 4;
    if (n0 >= N) return;
#pragma unroll
    for (int it = 0; it < 2; ++it) {
        int a = n0 + it * 2;
        if (a >= N) return;
        int bn = a + 1;
        bool hasB = bn < N;
        int cntA = deg[a];
        int cntB = hasB ? deg[bn] : 0;
        int rawA = csr_x[(a << 6) | lane];                 // coalesced 256B
        int rawB = hasB ? csr_x[(bn << 6) | lane] : 0;
        _Float16 selfA = h16[(long long)a * IN_FEAT + lane];
        _Float16 selfB = hasB ? h16[(long long)bn * IN_FEAT + lane] : (_Float16)0.0f;
        int mA = cntA < CAP ? cntA : CAP;
        int mB = cntB < CAP ? cntB : CAP;
        int sidA = (lane < mA) ? rawA : 0;
        int sidB = (lane < mB) ? rawB : 0;
        float accA0 = 0.f, accA1 = 0.f, accB0 = 0.f, accB1 = 0.f;
        int mmax = mA > mB ? mA : mB;
        for (int j = 0; j < mmax; j += 8) {
            float va[8], vb[8];
#pragma unroll
            for (int k = 0; k < 8; ++k) {
                int sA = __shfl(sidA, j + k);
                int sB = __shfl(sidB, j + k);
                va[k] = (float)h16[(long long)sA * IN_FEAT + lane];
                vb[k] = (float)h16[(long long)sB * IN_FEAT + lane];
            }
#pragma unroll
            for (int k = 0; k < 8; ++k) {
                // j+k, mA, mB wave-uniform -> scalar-predicated, no divergence
                float xa = (j + k < mA) ? va[k] : 0.0f;
                float xb = (j + k < mB) ? vb[k] : 0.0f;
                if (k & 1) { accA1 += xa; accB1 += xb; }
                else       { accA0 += xa; accB0 += xb; }
            }
        }
        float meanA = (accA0 + accA1) / fmaxf((float)cntA, 1.0f);
        _Float16* xrA = (_Float16*)(csr_x + ((long long)a << 6));
        xrA[lane] = selfA;
        xrA[IN_FEAT + lane] = (_Float16)meanA;
        if (hasB) {
            float meanB = (accB0 + accB1) / fmaxf((float)cntB, 1.0f);
            _Float16* xrB = (_Float16*)(csr_x + ((long long)bn << 6));
            xrB[lane] = selfB;
            xrB[IN_FEAT + lane] = (_Float16)meanB;
        }
    }
}

// ---- K3: MFMA linear. 16 nodes/wave, 4 waves/block. ----
// W fragments staged through LDS: the old prologue did 128 scattered 4B
// global loads/thread (51M segments kernel-wide, same scattered-transaction
// wall as fill). Now: 32 coalesced f32 loads/thread -> LDS in fragment
// order (once per block), then 16 conflict-free ds_read_b128/thread.
__global__ __launch_bounds__(256) void linear_kernel(const int* __restrict__ x_i,
        const float* __restrict__ W, const float* __restrict__ b,
        float* __restrict__ out, int N) {
    const _Float16* x = (const _Float16*)x_i;
    __shared__ _Float16 wlds[16 * 64 * 8];   // 16KB: [f=t*4+q][lane][j]
    int wave = threadIdx.x >> 6;
    int lane = threadIdx.x & 63;
    int quad = lane >> 4;
    int l16  = lane & 15;

    // cooperative W load: i = row*128+col, coalesced f32 reads.
    for (int i = threadIdx.x; i < 64 * 2 * IN_FEAT; i += 256) {
        int row = i >> 7, col = i & 127;
        int t = row >> 4, lr = row & 15;
        int q = col >> 5, qd = (col & 31) >> 3, j = col & 7;
        wlds[(((t * 4 + q) * 64) + (qd * 16 + lr)) * 8 + j] = (_Float16)W[i];
    }
    __syncthreads();

    int node_base = (blockIdx.x * 4 + wave) * 16;
    if (node_base >= N) return;   // after barrier: no partial-block deadlock

    half8 bf[4][4];
#pragma unroll
    for (int t = 0; t < 4; ++t)
#pragma unroll
        for (int q = 0; q < 4; ++q)
            bf[t][q] = *(const half8*)&wlds[((t * 4 + q) * 64 + lane) * 8];
    float bias[4];
#pragma unroll
    for (int t = 0; t < 4; ++t) bias[t] = b[16 * t + l16];

    int mrow = node_base + l16;
    if (mrow >= N) mrow = N - 1;

    floatx4 z = {0.0f, 0.0f, 0.0f, 0.0f};
    floatx4 acc[4] = {z, z, z, z};
#pragma unroll
    for (int q = 0; q < 4; ++q) {
        half8 af = *(const half8*)&x[(long long)mrow * (2 * IN_FEAT) + 32 * q + 8 * quad];
#pragma unroll
        for (int t = 0; t < 4; ++t)
            acc[t] = __builtin_amdgcn_mfma_f32_16x16x32_f16(af, bf[t][q], acc[t], 0, 0, 0);
    }
#pragma unroll
    for (int t = 0; t < 4; ++t)
#pragma unroll
        for (int r = 0; r < 4; ++r) {
            int n = node_base + quad * 4 + r;
            if (n < N)
                out[(long long)n * OUT_FEAT + 16 * t + l16] = acc[t][r] + bias[t];
        }
}

extern "C" void kernel_launch(void* const* d_in, const int* in_sizes, int n_in,
                              void* d_out, int out_size, void* d_ws, size_t ws_size,
                              hipStream_t stream) {
    const float* h   = (const float*)d_in[0];
    const int*   src = (const int*)d_in[1];
    const int*   dst = (const int*)d_in[2];
    const float* W   = (const float*)d_in[3];
    const float* b   = (const float*)d_in[4];
    float* out = (float*)d_out;

    int N = in_sizes[0] / IN_FEAT;   // 100000
    int E = in_sizes[1];             // 1600000

    // ws (ints): deg[N] | csr[N*64] (x[N][128] f16 aliased over csr) = 26 MB
    int* deg = (int*)d_ws;
    int* csr = deg + N;
    // h16 lives in the front 12.8 MB of d_out (dead until linear_kernel
    // rewrites d_out; linear reads only from ws -> no race).
    _Float16* h16 = (_Float16*)out;

    (void)hipMemsetAsync(deg, 0, (size_t)N * sizeof(int), stream);

    int total8 = N * IN_FEAT / 8;
    conv_kernel<<<(total8 + 255) / 256, 256, 0, stream>>>(h, h16, total8);

    int shard_sz = (N + NSHARD - 1) / NSHARD;   // 12500
    fill_kernel<<<NSHARD * BLKS_PER_SHARD, 256, 0, stream>>>(src, dst, deg, csr, E, shard_sz);

    int gather_blocks = (N + 15) / 16;       // 4 waves x 4 nodes (2 pairs)
    gather_kernel<<<gather_blocks, 256, 0, stream>>>(h16, deg, csr, N);

    int tiles = (N + 15) / 16;
    linear_kernel<<<(tiles + 3) / 4, 256, 0, stream>>>(csr, W, b, out, N);
}